// Round 1
// baseline (343.303 us; speedup 1.0000x reference)
//
#include <hip/hip_runtime.h>
#include <math.h>

// Problem constants (from setup_inputs): B=16, C=64, H=80, W=80, N=32
constexpr int B = 16, C = 64, H = 80, Wd = 80, N = 32;
constexpr int HW = H * Wd;          // 6400
constexpr int CHW = C * HW;         // 409600
constexpr long long TOTAL = (long long)B * CHW;  // 6,553,600

// Workspace layout:
//   [0, 8192)            : int4 assign[B*N]  {valid, mi, mj, lab}
//   [8192, 8192+12)      : float acc[3]      {sum_l1, sum_giou, sum_focal}
//   [8192+12, 8192+16)   : int   npos

// ---------------------------------------------------------------------------
// Kernel 1: per (b,g) argmax-GIoU assignment. One block per (b,g).
// GIoU computed with contract(off) + exact numpy op order so the float32
// values (and argmax/first-tie semantics) match the reference bitwise.
// ---------------------------------------------------------------------------
__global__ __launch_bounds__(256) void assign_kernel(
    const float* __restrict__ pred,   // [B,C,H,W,4]
    const float* __restrict__ gtb,    // [B,N,4]
    const int*   __restrict__ gtl,    // [B,N]
    int4* __restrict__ assign,
    int* __restrict__ acc_zero)       // zero the accumulator region
{
#pragma clang fp contract(off)
    const int bg = blockIdx.x;
    const int b = bg >> 5;
    const int g = bg & 31;
    const int tid = threadIdx.x;

    if (bg == 0 && tid < 8) acc_zero[tid] = 0;   // zero accs (poisoned 0xAA)

    const int lab = gtl[b * N + g];
    const float4 gb = ((const float4*)gtb)[b * N + g];
    const float a2 = (gb.z - gb.x) * (gb.w - gb.y);

    const float4* pc = (const float4*)(pred + (size_t)(b * C + lab) * HW * 4);

    float best = -INFINITY;
    int bidx = 0x7fffffff;
    for (int p = tid; p < HW; p += 256) {
        float4 pb = pc[p];
        float a1 = (pb.z - pb.x) * (pb.w - pb.y);
        float ltx = fmaxf(pb.x, gb.x), lty = fmaxf(pb.y, gb.y);
        float rbx = fminf(pb.z, gb.z), rby = fminf(pb.w, gb.w);
        float wx = fmaxf(rbx - ltx, 0.0f), wy = fmaxf(rby - lty, 0.0f);
        float inter = wx * wy;
        float uni = (a1 + a2) - inter;
        float iou = inter / uni;
        float lex = fminf(pb.x, gb.x), ley = fminf(pb.y, gb.y);
        float rex = fmaxf(pb.z, gb.z), rey = fmaxf(pb.w, gb.w);
        float ex = fmaxf(rex - lex, 0.0f), ey = fmaxf(rey - ley, 0.0f);
        float ae = ex * ey;
        float gi = iou - (ae - uni) / ae;
        if (gi > best) { best = gi; bidx = p; }   // strict > keeps first index
    }

    __shared__ float sv[256];
    __shared__ int   si[256];
    sv[tid] = best; si[tid] = bidx;
    __syncthreads();
    for (int s = 128; s > 0; s >>= 1) {
        if (tid < s) {
            float v2 = sv[tid + s]; int i2 = si[tid + s];
            float v1 = sv[tid];     int i1 = si[tid];
            if (v2 > v1 || (v2 == v1 && i2 < i1)) { sv[tid] = v2; si[tid] = i2; }
        }
        __syncthreads();
    }
    if (tid == 0) {
        int idx = si[0];
        float v = sv[0];
        int4 r;
        r.x = (v > 0.3f) ? 1 : 0;   // valid
        r.y = idx / Wd;             // mi
        r.z = idx % Wd;             // mj
        r.w = lab;
        assign[bg] = r;
    }
}

// ---------------------------------------------------------------------------
// Kernel 2: dense pass over all B*C*H*W positions.
// Focal loss everywhere; L1 + GIoU only at positive positions (rare).
// Per-block LDS list of gts filtered to this block's <=2 channels.
// ---------------------------------------------------------------------------
constexpr int K2_PER_THREAD = 8;
constexpr int K2_BLOCK_ELEMS = 256 * K2_PER_THREAD;          // 2048
constexpr int K2_BLOCKS_PER_BATCH = CHW / K2_BLOCK_ELEMS;    // 200

__global__ __launch_bounds__(256) void main_kernel(
    const float* __restrict__ pred,
    const float* __restrict__ conf,
    const float* __restrict__ gtb,
    const int4*  __restrict__ assign,
    float* __restrict__ accs,         // {sum_l1, sum_giou, sum_focal}
    int*   __restrict__ npos_acc)
{
    const int tid = threadIdx.x;
    const int b = blockIdx.x / K2_BLOCKS_PER_BATCH;
    const int base = (blockIdx.x % K2_BLOCKS_PER_BATCH) * K2_BLOCK_ELEMS;

    __shared__ int s_cnt;
    __shared__ int4 s_gt[N];   // {g, lab, mi, mj} for valid gts in channel range
    if (tid == 0) s_cnt = 0;
    __syncthreads();
    const int c0 = base / HW;
    const int c1 = (base + K2_BLOCK_ELEMS - 1) / HW;
    if (tid < N) {
        int4 a = assign[b * N + tid];
        if (a.x && a.w >= c0 && a.w <= c1) {
            int k = atomicAdd(&s_cnt, 1);
            s_gt[k] = make_int4(tid, a.w, a.y, a.z);
        }
    }
    __syncthreads();
    const int cnt = s_cnt;

    float l_l1 = 0.0f, l_gi = 0.0f, l_f = 0.0f;
    int l_np = 0;

    for (int k = 0; k < K2_PER_THREAD; k++) {
        const int pos = base + tid + k * 256;
        const int c = pos / HW;
        const int rem = pos - c * HW;
        const int h = rem / Wd;
        const int w = rem - h * Wd;

        int m = -1;
        for (int j = 0; j < cnt; j++) {
            int4 a = s_gt[j];
            if (a.y == c && h >= a.z - 2 && h <= a.z + 1 &&
                w >= a.w - 2 && w <= a.w + 1)
                m = max(m, a.x);
        }

        float p = conf[(size_t)b * CHW + pos];
        p = fminf(fmaxf(p, 1e-6f), 1.0f - 1e-6f);

        if (m >= 0) {
            // positive: focal with t=1, plus L1 + GIoU
            float om = 1.0f - p;
            l_f += 0.25f * om * om * (-logf(p));
            l_np++;

            float4 pb = *(const float4*)(pred + ((size_t)b * CHW + pos) * 4);
            float4 gb = ((const float4*)gtb)[b * N + m];
            l_l1 += 0.25f * (fabsf(pb.x - gb.x) + fabsf(pb.y - gb.y) +
                             fabsf(pb.z - gb.z) + fabsf(pb.w - gb.w));

            float a1 = (pb.z - pb.x) * (pb.w - pb.y);
            float a2 = (gb.z - gb.x) * (gb.w - gb.y);
            float ltx = fmaxf(pb.x, gb.x), lty = fmaxf(pb.y, gb.y);
            float rbx = fminf(pb.z, gb.z), rby = fminf(pb.w, gb.w);
            float wx = fmaxf(rbx - ltx, 0.0f), wy = fmaxf(rby - lty, 0.0f);
            float inter = wx * wy;
            float uni = (a1 + a2) - inter;
            float iou = inter / uni;
            float lex = fminf(pb.x, gb.x), ley = fminf(pb.y, gb.y);
            float rex = fmaxf(pb.z, gb.z), rey = fmaxf(pb.w, gb.w);
            float ex = fmaxf(rex - lex, 0.0f), ey = fmaxf(rey - ley, 0.0f);
            float ae = ex * ey;
            float gi = iou - (ae - uni) / ae;
            l_gi += 1.0f - gi;
        } else {
            // negative: focal with t=0
            l_f += 0.75f * p * p * (-log1pf(-p));
        }
    }

    // block reduction
    __shared__ float r0[256], r1[256], r2[256];
    __shared__ int ri[256];
    r0[tid] = l_l1; r1[tid] = l_gi; r2[tid] = l_f; ri[tid] = l_np;
    __syncthreads();
    for (int s = 128; s > 0; s >>= 1) {
        if (tid < s) {
            r0[tid] += r0[tid + s];
            r1[tid] += r1[tid + s];
            r2[tid] += r2[tid + s];
            ri[tid] += ri[tid + s];
        }
        __syncthreads();
    }
    if (tid == 0) {
        atomicAdd(&accs[0], r0[0]);
        atomicAdd(&accs[1], r1[0]);
        atomicAdd(&accs[2], r2[0]);
        atomicAdd(npos_acc, ri[0]);
    }
}

// ---------------------------------------------------------------------------
// Kernel 3: finalize 5 scalars.
// ---------------------------------------------------------------------------
__global__ void final_kernel(const float* __restrict__ accs,
                             const int* __restrict__ npos,
                             float* __restrict__ out)
{
    float sl1 = accs[0], sgi = accs[1], sf = accs[2];
    int np = *npos;
    float denom = fmaxf((float)np, 1.0f);
    float l1 = sl1 / denom;
    float gi = sgi / denom;
    float cf = sf / (float)TOTAL;
    out[0] = l1;
    out[1] = gi;
    out[2] = cf;
    out[3] = l1 + 2.0f * gi + cf;
    out[4] = (float)np / (float)TOTAL;
}

extern "C" void kernel_launch(void* const* d_in, const int* in_sizes, int n_in,
                              void* d_out, int out_size, void* d_ws, size_t ws_size,
                              hipStream_t stream) {
    const float* pred = (const float*)d_in[0];  // [B,C,H,W,4]
    const float* conf = (const float*)d_in[1];  // [B,C,H,W]
    // d_in[2] = cam: unused by the loss
    const float* gtb  = (const float*)d_in[3];  // [B,N,4]
    const int*   gtl  = (const int*)d_in[4];    // [B,N]

    int4*  assign   = (int4*)d_ws;
    float* accs     = (float*)((char*)d_ws + 8192);
    int*   npos_acc = (int*)((char*)d_ws + 8192 + 12);
    float* out      = (float*)d_out;

    assign_kernel<<<B * N, 256, 0, stream>>>(pred, gtb, gtl, assign, (int*)accs);
    main_kernel<<<B * K2_BLOCKS_PER_BATCH, 256, 0, stream>>>(
        pred, conf, gtb, assign, accs, npos_acc);
    final_kernel<<<1, 1, 0, stream>>>(accs, npos_acc, out);
}

// Round 2
// 337.427 us; speedup vs baseline: 1.0174x; 1.0174x over previous
//
#include <hip/hip_runtime.h>
#include <math.h>

// Problem constants (from setup_inputs): B=16, C=64, H=80, W=80, N=32
constexpr int B = 16, C = 64, H = 80, Wd = 80, N = 32;
constexpr int HW = H * Wd;          // 6400
constexpr int CHW = C * HW;         // 409600
constexpr long long TOTAL = (long long)B * CHW;  // 6,553,600

// Workspace layout:
//   [0, 8192)            : int4 assign[B*N]  {valid, mi, mj, lab}
//   [8192, 8192+12)      : float acc[3]      {sum_l1, sum_giou, sum_focal}
//   [8192+12, 8192+16)   : int   npos

// ---------------------------------------------------------------------------
// Kernel 1: per (b,g) argmax-GIoU assignment. One block per (b,g).
// All 25 float4 loads per thread are prefetched into registers first so the
// memory pipe overlaps them (latency-bound -> BW-bound). GIoU math uses
// contract(off) + exact numpy op order so float32 values (and argmax
// first-index tie-break) match the reference bitwise.
// ---------------------------------------------------------------------------
constexpr int A_ITER = HW / 256;   // 25

__global__ __launch_bounds__(256) void assign_kernel(
    const float* __restrict__ pred,   // [B,C,H,W,4]
    const float* __restrict__ gtb,    // [B,N,4]
    const int*   __restrict__ gtl,    // [B,N]
    int4* __restrict__ assign,
    int* __restrict__ acc_zero)       // zero the accumulator region
{
#pragma clang fp contract(off)
    const int bg = blockIdx.x;
    const int b = bg >> 5;
    const int g = bg & 31;
    const int tid = threadIdx.x;

    if (bg == 0 && tid < 4) acc_zero[tid] = 0;   // zero accs (poisoned 0xAA)

    const int lab = gtl[b * N + g];
    const float4 gb = ((const float4*)gtb)[b * N + g];
    const float a2 = (gb.z - gb.x) * (gb.w - gb.y);

    const float4* pc = (const float4*)(pred + (size_t)(b * C + lab) * HW * 4);

    // ---- prefetch phase: 25 independent vector loads in flight ----
    float4 buf[A_ITER];
#pragma unroll
    for (int k = 0; k < A_ITER; k++)
        buf[k] = pc[tid + k * 256];

    // ---- compute phase ----
    float best = -INFINITY;
    int bidx = 0x7fffffff;
#pragma unroll
    for (int k = 0; k < A_ITER; k++) {
        float4 pb = buf[k];
        float a1 = (pb.z - pb.x) * (pb.w - pb.y);
        float ltx = fmaxf(pb.x, gb.x), lty = fmaxf(pb.y, gb.y);
        float rbx = fminf(pb.z, gb.z), rby = fminf(pb.w, gb.w);
        float wx = fmaxf(rbx - ltx, 0.0f), wy = fmaxf(rby - lty, 0.0f);
        float inter = wx * wy;
        float uni = (a1 + a2) - inter;
        float iou = inter / uni;
        float lex = fminf(pb.x, gb.x), ley = fminf(pb.y, gb.y);
        float rex = fmaxf(pb.z, gb.z), rey = fmaxf(pb.w, gb.w);
        float ex = fmaxf(rex - lex, 0.0f), ey = fmaxf(rey - ley, 0.0f);
        float ae = ex * ey;
        float gi = iou - (ae - uni) / ae;
        if (gi > best) { best = gi; bidx = tid + k * 256; }  // strict >: first idx
    }

    __shared__ float sv[256];
    __shared__ int   si[256];
    sv[tid] = best; si[tid] = bidx;
    __syncthreads();
    for (int s = 128; s > 0; s >>= 1) {
        if (tid < s) {
            float v2 = sv[tid + s]; int i2 = si[tid + s];
            float v1 = sv[tid];     int i1 = si[tid];
            if (v2 > v1 || (v2 == v1 && i2 < i1)) { sv[tid] = v2; si[tid] = i2; }
        }
        __syncthreads();
    }
    if (tid == 0) {
        int idx = si[0];
        float v = sv[0];
        int4 r;
        r.x = (v > 0.3f) ? 1 : 0;   // valid
        r.y = idx / Wd;             // mi
        r.z = idx % Wd;             // mj
        r.w = lab;
        assign[bg] = r;
    }
}

// ---------------------------------------------------------------------------
// Kernel 2: dense pass. Each thread owns 8 CONTIGUOUS positions (8|6400 and
// 8|80 => all 8 share one (c,h); w = w0..w0+7). conf is read as two
// back-to-back float4 -> one memory round-trip per thread instead of eight.
// ---------------------------------------------------------------------------
constexpr int K2_PER_THREAD = 8;
constexpr int K2_BLOCK_ELEMS = 256 * K2_PER_THREAD;          // 2048
constexpr int K2_BLOCKS_PER_BATCH = CHW / K2_BLOCK_ELEMS;    // 200

__global__ __launch_bounds__(256) void main_kernel(
    const float* __restrict__ pred,
    const float* __restrict__ conf,
    const float* __restrict__ gtb,
    const int4*  __restrict__ assign,
    float* __restrict__ accs,         // {sum_l1, sum_giou, sum_focal}
    int*   __restrict__ npos_acc)
{
    const int tid = threadIdx.x;
    const int b = blockIdx.x / K2_BLOCKS_PER_BATCH;
    const int base = (blockIdx.x % K2_BLOCKS_PER_BATCH) * K2_BLOCK_ELEMS;
    const int pos0 = base + tid * K2_PER_THREAD;   // contiguous span of 8

    // ---- issue conf loads immediately (before any LDS/barrier work) ----
    const float4* conf4 = (const float4*)(conf + (size_t)b * CHW);
    float4 p0 = conf4[(pos0 >> 2)];
    float4 p1 = conf4[(pos0 >> 2) + 1];

    // span geometry: all 8 elements share one channel and one row
    const int c = pos0 / HW;
    const int rem = pos0 - c * HW;
    const int h = rem / Wd;
    const int w0 = rem - h * Wd;

    __shared__ int s_cnt;
    __shared__ int4 s_gt[N];   // {g, lab, mi, mj} for valid gts in channel range
    if (tid == 0) s_cnt = 0;
    __syncthreads();
    const int c0 = base / HW;
    const int c1 = (base + K2_BLOCK_ELEMS - 1) / HW;
    if (tid < N) {
        int4 a = assign[b * N + tid];
        if (a.x && a.w >= c0 && a.w <= c1) {
            int k = atomicAdd(&s_cnt, 1);
            s_gt[k] = make_int4(tid, a.w, a.y, a.z);
        }
    }
    __syncthreads();
    const int cnt = s_cnt;

    // match per element
    int m[K2_PER_THREAD];
#pragma unroll
    for (int e = 0; e < K2_PER_THREAD; e++) m[e] = -1;
    for (int j = 0; j < cnt; j++) {
        int4 a = s_gt[j];
        if (a.y == c && h >= a.z - 2 && h <= a.z + 1) {
#pragma unroll
            for (int e = 0; e < K2_PER_THREAD; e++) {
                int w = w0 + e;
                if (w >= a.w - 2 && w <= a.w + 1) m[e] = max(m[e], a.x);
            }
        }
    }

    float pv[K2_PER_THREAD] = {p0.x, p0.y, p0.z, p0.w, p1.x, p1.y, p1.z, p1.w};

    float l_l1 = 0.0f, l_gi = 0.0f, l_f = 0.0f;
    int l_np = 0;

#pragma unroll
    for (int e = 0; e < K2_PER_THREAD; e++) {
        float p = fminf(fmaxf(pv[e], 1e-6f), 1.0f - 1e-6f);
        if (m[e] >= 0) {
            // positive: focal with t=1, plus L1 + GIoU (rare path)
            float om = 1.0f - p;
            l_f += 0.25f * om * om * (-logf(p));
            l_np++;

            int pos = pos0 + e;
            float4 pb = *(const float4*)(pred + ((size_t)b * CHW + pos) * 4);
            float4 gb = ((const float4*)gtb)[b * N + m[e]];
            l_l1 += 0.25f * (fabsf(pb.x - gb.x) + fabsf(pb.y - gb.y) +
                             fabsf(pb.z - gb.z) + fabsf(pb.w - gb.w));

            float a1 = (pb.z - pb.x) * (pb.w - pb.y);
            float a2 = (gb.z - gb.x) * (gb.w - gb.y);
            float ltx = fmaxf(pb.x, gb.x), lty = fmaxf(pb.y, gb.y);
            float rbx = fminf(pb.z, gb.z), rby = fminf(pb.w, gb.w);
            float wx = fmaxf(rbx - ltx, 0.0f), wy = fmaxf(rby - lty, 0.0f);
            float inter = wx * wy;
            float uni = (a1 + a2) - inter;
            float iou = inter / uni;
            float lex = fminf(pb.x, gb.x), ley = fminf(pb.y, gb.y);
            float rex = fmaxf(pb.z, gb.z), rey = fmaxf(pb.w, gb.w);
            float ex = fmaxf(rex - lex, 0.0f), ey = fmaxf(rey - ley, 0.0f);
            float ae = ex * ey;
            float gi = iou - (ae - uni) / ae;
            l_gi += 1.0f - gi;
        } else {
            // negative: focal with t=0
            l_f += 0.75f * p * p * (-log1pf(-p));
        }
    }

    // block reduction
    __shared__ float r0[256], r1[256], r2[256];
    __shared__ int ri[256];
    r0[tid] = l_l1; r1[tid] = l_gi; r2[tid] = l_f; ri[tid] = l_np;
    __syncthreads();
    for (int s = 128; s > 0; s >>= 1) {
        if (tid < s) {
            r0[tid] += r0[tid + s];
            r1[tid] += r1[tid + s];
            r2[tid] += r2[tid + s];
            ri[tid] += ri[tid + s];
        }
        __syncthreads();
    }
    if (tid == 0) {
        atomicAdd(&accs[0], r0[0]);
        atomicAdd(&accs[1], r1[0]);
        atomicAdd(&accs[2], r2[0]);
        atomicAdd(npos_acc, ri[0]);
    }
}

// ---------------------------------------------------------------------------
// Kernel 3: finalize 5 scalars.
// ---------------------------------------------------------------------------
__global__ void final_kernel(const float* __restrict__ accs,
                             const int* __restrict__ npos,
                             float* __restrict__ out)
{
    float sl1 = accs[0], sgi = accs[1], sf = accs[2];
    int np = *npos;
    float denom = fmaxf((float)np, 1.0f);
    float l1 = sl1 / denom;
    float gi = sgi / denom;
    float cf = sf / (float)TOTAL;
    out[0] = l1;
    out[1] = gi;
    out[2] = cf;
    out[3] = l1 + 2.0f * gi + cf;
    out[4] = (float)np / (float)TOTAL;
}

extern "C" void kernel_launch(void* const* d_in, const int* in_sizes, int n_in,
                              void* d_out, int out_size, void* d_ws, size_t ws_size,
                              hipStream_t stream) {
    const float* pred = (const float*)d_in[0];  // [B,C,H,W,4]
    const float* conf = (const float*)d_in[1];  // [B,C,H,W]
    // d_in[2] = cam: unused by the loss
    const float* gtb  = (const float*)d_in[3];  // [B,N,4]
    const int*   gtl  = (const int*)d_in[4];    // [B,N]

    int4*  assign   = (int4*)d_ws;
    float* accs     = (float*)((char*)d_ws + 8192);
    int*   npos_acc = (int*)((char*)d_ws + 8192 + 12);
    float* out      = (float*)d_out;

    assign_kernel<<<B * N, 256, 0, stream>>>(pred, gtb, gtl, assign, (int*)accs);
    main_kernel<<<B * K2_BLOCKS_PER_BATCH, 256, 0, stream>>>(
        pred, conf, gtb, assign, accs, npos_acc);
    final_kernel<<<1, 1, 0, stream>>>(accs, npos_acc, out);
}

// Round 3
// 210.771 us; speedup vs baseline: 1.6288x; 1.6009x over previous
//
#include <hip/hip_runtime.h>
#include <math.h>

// Problem constants (from setup_inputs): B=16, C=64, H=80, W=80, N=32
constexpr int B = 16, C = 64, H = 80, Wd = 80, N = 32;
constexpr int HW = H * Wd;          // 6400
constexpr int CHW = C * HW;         // 409600
constexpr long long TOTAL = (long long)B * CHW;  // 6,553,600

// Workspace layout:
//   [0, 8192)            : int4 assign[B*N]  {valid, mi, mj, lab}
//   [8192, 8192+NBLK*16) : float4 partials[NBLK]  {l1, giou, focal, npos}

// ---------------------------------------------------------------------------
// Kernel 1: per (b,g) argmax-GIoU assignment. One block per (b,g).
// All 25 float4 loads per thread prefetched into registers (latency overlap).
// GIoU math uses contract(off) + exact numpy op order so float32 values (and
// argmax first-index tie-break) match the reference bitwise.
// ---------------------------------------------------------------------------
constexpr int A_ITER = HW / 256;   // 25

__global__ __launch_bounds__(256) void assign_kernel(
    const float* __restrict__ pred,   // [B,C,H,W,4]
    const float* __restrict__ gtb,    // [B,N,4]
    const int*   __restrict__ gtl,    // [B,N]
    int4* __restrict__ assign)
{
#pragma clang fp contract(off)
    const int bg = blockIdx.x;
    const int b = bg >> 5;
    const int g = bg & 31;
    const int tid = threadIdx.x;

    const int lab = gtl[b * N + g];
    const float4 gb = ((const float4*)gtb)[b * N + g];
    const float a2 = (gb.z - gb.x) * (gb.w - gb.y);

    const float4* pc = (const float4*)(pred + (size_t)(b * C + lab) * HW * 4);

    // ---- prefetch phase: 25 independent vector loads in flight ----
    float4 buf[A_ITER];
#pragma unroll
    for (int k = 0; k < A_ITER; k++)
        buf[k] = pc[tid + k * 256];

    // ---- compute phase ----
    float best = -INFINITY;
    int bidx = 0x7fffffff;
#pragma unroll
    for (int k = 0; k < A_ITER; k++) {
        float4 pb = buf[k];
        float a1 = (pb.z - pb.x) * (pb.w - pb.y);
        float ltx = fmaxf(pb.x, gb.x), lty = fmaxf(pb.y, gb.y);
        float rbx = fminf(pb.z, gb.z), rby = fminf(pb.w, gb.w);
        float wx = fmaxf(rbx - ltx, 0.0f), wy = fmaxf(rby - lty, 0.0f);
        float inter = wx * wy;
        float uni = (a1 + a2) - inter;
        float iou = inter / uni;
        float lex = fminf(pb.x, gb.x), ley = fminf(pb.y, gb.y);
        float rex = fmaxf(pb.z, gb.z), rey = fmaxf(pb.w, gb.w);
        float ex = fmaxf(rex - lex, 0.0f), ey = fmaxf(rey - ley, 0.0f);
        float ae = ex * ey;
        float gi = iou - (ae - uni) / ae;
        if (gi > best) { best = gi; bidx = tid + k * 256; }  // strict >: first idx
    }

    __shared__ float sv[256];
    __shared__ int   si[256];
    sv[tid] = best; si[tid] = bidx;
    __syncthreads();
    for (int s = 128; s > 0; s >>= 1) {
        if (tid < s) {
            float v2 = sv[tid + s]; int i2 = si[tid + s];
            float v1 = sv[tid];     int i1 = si[tid];
            if (v2 > v1 || (v2 == v1 && i2 < i1)) { sv[tid] = v2; si[tid] = i2; }
        }
        __syncthreads();
    }
    if (tid == 0) {
        int idx = si[0];
        float v = sv[0];
        int4 r;
        r.x = (v > 0.3f) ? 1 : 0;   // valid
        r.y = idx / Wd;             // mi
        r.z = idx % Wd;             // mj
        r.w = lab;
        assign[bg] = r;
    }
}

// ---------------------------------------------------------------------------
// Kernel 2: dense pass. Each thread owns 16 CONTIGUOUS positions (16|80 =>
// all 16 share one (c,h) row). NO global atomics: each block writes one
// float4 partial {l1, giou, focal, npos} to its own workspace slot.
// ---------------------------------------------------------------------------
constexpr int K2_PER_THREAD = 16;
constexpr int K2_BLOCK_ELEMS = 256 * K2_PER_THREAD;          // 4096
constexpr int K2_BLOCKS_PER_BATCH = CHW / K2_BLOCK_ELEMS;    // 100
constexpr int NBLK = B * K2_BLOCKS_PER_BATCH;                // 1600

__global__ __launch_bounds__(256) void main_kernel(
    const float* __restrict__ pred,
    const float* __restrict__ conf,
    const float* __restrict__ gtb,
    const int4*  __restrict__ assign,
    float4* __restrict__ partials)
{
    const int tid = threadIdx.x;
    const int b = blockIdx.x / K2_BLOCKS_PER_BATCH;
    const int base = (blockIdx.x % K2_BLOCKS_PER_BATCH) * K2_BLOCK_ELEMS;
    const int pos0 = base + tid * K2_PER_THREAD;   // contiguous span of 16

    // ---- issue conf loads immediately ----
    const float4* conf4 = (const float4*)(conf + (size_t)b * CHW);
    float4 q[4];
#pragma unroll
    for (int k = 0; k < 4; k++) q[k] = conf4[(pos0 >> 2) + k];

    // span geometry: all 16 elements share one channel and one row
    const int c = pos0 / HW;
    const int rem = pos0 - c * HW;
    const int h = rem / Wd;
    const int w0 = rem - h * Wd;

    __shared__ int s_cnt;
    __shared__ int4 s_gt[N];   // {g, lab, mi, mj} for valid gts in channel range
    if (tid == 0) s_cnt = 0;
    __syncthreads();
    const int c0 = base / HW;
    const int c1 = (base + K2_BLOCK_ELEMS - 1) / HW;
    if (tid < N) {
        int4 a = assign[b * N + tid];
        if (a.x && a.w >= c0 && a.w <= c1) {
            int k = atomicAdd(&s_cnt, 1);    // LDS atomic, fine
            s_gt[k] = make_int4(tid, a.w, a.y, a.z);
        }
    }
    __syncthreads();
    const int cnt = s_cnt;

    // match per element
    int m[K2_PER_THREAD];
#pragma unroll
    for (int e = 0; e < K2_PER_THREAD; e++) m[e] = -1;
    for (int j = 0; j < cnt; j++) {
        int4 a = s_gt[j];
        if (a.y == c && h >= a.z - 2 && h <= a.z + 1) {
#pragma unroll
            for (int e = 0; e < K2_PER_THREAD; e++) {
                int w = w0 + e;
                if (w >= a.w - 2 && w <= a.w + 1) m[e] = max(m[e], a.x);
            }
        }
    }

    float pv[K2_PER_THREAD];
#pragma unroll
    for (int k = 0; k < 4; k++) {
        pv[4 * k + 0] = q[k].x; pv[4 * k + 1] = q[k].y;
        pv[4 * k + 2] = q[k].z; pv[4 * k + 3] = q[k].w;
    }

    float l_l1 = 0.0f, l_gi = 0.0f, l_f = 0.0f, l_np = 0.0f;

#pragma unroll
    for (int e = 0; e < K2_PER_THREAD; e++) {
        float p = fminf(fmaxf(pv[e], 1e-6f), 1.0f - 1e-6f);
        if (m[e] >= 0) {
#pragma clang fp contract(off)
            // positive: focal with t=1, plus L1 + GIoU (rare path)
            float om = 1.0f - p;
            l_f += 0.25f * om * om * (-logf(p));
            l_np += 1.0f;

            int pos = pos0 + e;
            float4 pb = *(const float4*)(pred + ((size_t)b * CHW + pos) * 4);
            float4 gb = ((const float4*)gtb)[b * N + m[e]];
            l_l1 += 0.25f * (fabsf(pb.x - gb.x) + fabsf(pb.y - gb.y) +
                             fabsf(pb.z - gb.z) + fabsf(pb.w - gb.w));

            float a1 = (pb.z - pb.x) * (pb.w - pb.y);
            float a2 = (gb.z - gb.x) * (gb.w - gb.y);
            float ltx = fmaxf(pb.x, gb.x), lty = fmaxf(pb.y, gb.y);
            float rbx = fminf(pb.z, gb.z), rby = fminf(pb.w, gb.w);
            float wx = fmaxf(rbx - ltx, 0.0f), wy = fmaxf(rby - lty, 0.0f);
            float inter = wx * wy;
            float uni = (a1 + a2) - inter;
            float iou = inter / uni;
            float lex = fminf(pb.x, gb.x), ley = fminf(pb.y, gb.y);
            float rex = fmaxf(pb.z, gb.z), rey = fmaxf(pb.w, gb.w);
            float ex = fmaxf(rex - lex, 0.0f), ey = fmaxf(rey - ley, 0.0f);
            float ae = ex * ey;
            float gi = iou - (ae - uni) / ae;
            l_gi += 1.0f - gi;
        } else {
            // negative: focal with t=0
            l_f += 0.75f * p * p * (-log1pf(-p));
        }
    }

    // block reduction -> single float4 partial per block (no global atomics)
    __shared__ float r0[256], r1[256], r2[256], r3[256];
    r0[tid] = l_l1; r1[tid] = l_gi; r2[tid] = l_f; r3[tid] = l_np;
    __syncthreads();
    for (int s = 128; s > 0; s >>= 1) {
        if (tid < s) {
            r0[tid] += r0[tid + s];
            r1[tid] += r1[tid + s];
            r2[tid] += r2[tid + s];
            r3[tid] += r3[tid + s];
        }
        __syncthreads();
    }
    if (tid == 0)
        partials[blockIdx.x] = make_float4(r0[0], r1[0], r2[0], r3[0]);
}

// ---------------------------------------------------------------------------
// Kernel 3: reduce NBLK partials, finalize 5 scalars. One block, 256 threads.
// ---------------------------------------------------------------------------
__global__ __launch_bounds__(256) void final_kernel(
    const float4* __restrict__ partials,
    float* __restrict__ out)
{
    const int tid = threadIdx.x;
    float s0 = 0.0f, s1 = 0.0f, s2 = 0.0f, s3 = 0.0f;
    for (int i = tid; i < NBLK; i += 256) {
        float4 p = partials[i];
        s0 += p.x; s1 += p.y; s2 += p.z; s3 += p.w;
    }
    __shared__ float r0[256], r1[256], r2[256], r3[256];
    r0[tid] = s0; r1[tid] = s1; r2[tid] = s2; r3[tid] = s3;
    __syncthreads();
    for (int s = 128; s > 0; s >>= 1) {
        if (tid < s) {
            r0[tid] += r0[tid + s];
            r1[tid] += r1[tid + s];
            r2[tid] += r2[tid + s];
            r3[tid] += r3[tid + s];
        }
        __syncthreads();
    }
    if (tid == 0) {
        float np = r3[0];
        float denom = fmaxf(np, 1.0f);
        float l1 = r0[0] / denom;
        float gi = r1[0] / denom;
        float cf = r2[0] / (float)TOTAL;
        out[0] = l1;
        out[1] = gi;
        out[2] = cf;
        out[3] = l1 + 2.0f * gi + cf;
        out[4] = np / (float)TOTAL;
    }
}

extern "C" void kernel_launch(void* const* d_in, const int* in_sizes, int n_in,
                              void* d_out, int out_size, void* d_ws, size_t ws_size,
                              hipStream_t stream) {
    const float* pred = (const float*)d_in[0];  // [B,C,H,W,4]
    const float* conf = (const float*)d_in[1];  // [B,C,H,W]
    // d_in[2] = cam: unused by the loss
    const float* gtb  = (const float*)d_in[3];  // [B,N,4]
    const int*   gtl  = (const int*)d_in[4];    // [B,N]

    int4*   assign   = (int4*)d_ws;
    float4* partials = (float4*)((char*)d_ws + 8192);
    float*  out      = (float*)d_out;

    assign_kernel<<<B * N, 256, 0, stream>>>(pred, gtb, gtl, assign);
    main_kernel<<<NBLK, 256, 0, stream>>>(pred, conf, gtb, assign, partials);
    final_kernel<<<1, 256, 0, stream>>>(partials, out);
}

// Round 4
// 190.140 us; speedup vs baseline: 1.8055x; 1.1085x over previous
//
#include <hip/hip_runtime.h>
#include <math.h>

// Problem constants (from setup_inputs): B=16, C=64, H=80, W=80, N=32
constexpr int B = 16, C = 64, H = 80, Wd = 80, N = 32;
constexpr int HW = H * Wd;          // 6400
constexpr int CHW = C * HW;         // 409600
constexpr long long TOTAL = (long long)B * CHW;  // 6,553,600

// Argmax split: 5 chunks of 1280 positions per (b,g)
constexpr int NCHUNK = 5;
constexpr int CHUNK_ELEMS = HW / NCHUNK;   // 1280
constexpr int A_DEPTH = CHUNK_ELEMS / 256; // 5 float4 per thread (20 VGPRs, no spill)

// Workspace layout:
//   [0, 512*5*8)         : int2 amax[B*N*NCHUNK]  {bits(best_giou), idx}
//   [32768, +NBLK*16)    : float4 partials[NBLK]  {l1, giou, focal, npos}

// ---------------------------------------------------------------------------
// Kernel 1 (stage A): per (b,g,chunk) partial argmax-GIoU. 2560 blocks.
// Small prefetch depth (5) keeps VGPRs low -> no scratch spill, 10 blocks/CU.
// GIoU math: contract(off) + exact numpy op order -> bitwise-identical values,
// so argmax with first-index tie-break matches the reference.
// ---------------------------------------------------------------------------
__global__ __launch_bounds__(256) void assign_partial_kernel(
    const float* __restrict__ pred,   // [B,C,H,W,4]
    const float* __restrict__ gtb,    // [B,N,4]
    const int*   __restrict__ gtl,    // [B,N]
    int2* __restrict__ amax)          // [B*N*NCHUNK]
{
#pragma clang fp contract(off)
    const int blk = blockIdx.x;
    const int bg = blk / NCHUNK;          // 0..511
    const int chunk = blk - bg * NCHUNK;  // 0..4
    const int b = bg >> 5;
    const int tid = threadIdx.x;

    const int lab = gtl[bg];
    const float4 gb = ((const float4*)gtb)[bg];
    const float a2 = (gb.z - gb.x) * (gb.w - gb.y);

    const float4* pc = (const float4*)(pred + (size_t)(b * C + lab) * HW * 4)
                       + chunk * CHUNK_ELEMS;

    // prefetch: 5 independent 16B loads in flight
    float4 buf[A_DEPTH];
#pragma unroll
    for (int k = 0; k < A_DEPTH; k++)
        buf[k] = pc[tid + k * 256];

    float best = -INFINITY;
    int bidx = 0x7fffffff;
#pragma unroll
    for (int k = 0; k < A_DEPTH; k++) {
        float4 pb = buf[k];
        float a1 = (pb.z - pb.x) * (pb.w - pb.y);
        float ltx = fmaxf(pb.x, gb.x), lty = fmaxf(pb.y, gb.y);
        float rbx = fminf(pb.z, gb.z), rby = fminf(pb.w, gb.w);
        float wx = fmaxf(rbx - ltx, 0.0f), wy = fmaxf(rby - lty, 0.0f);
        float inter = wx * wy;
        float uni = (a1 + a2) - inter;
        float iou = inter / uni;
        float lex = fminf(pb.x, gb.x), ley = fminf(pb.y, gb.y);
        float rex = fmaxf(pb.z, gb.z), rey = fmaxf(pb.w, gb.w);
        float ex = fmaxf(rex - lex, 0.0f), ey = fmaxf(rey - ley, 0.0f);
        float ae = ex * ey;
        float gi = iou - (ae - uni) / ae;
        if (gi > best) { best = gi; bidx = chunk * CHUNK_ELEMS + tid + k * 256; }
    }

    __shared__ float sv[256];
    __shared__ int   si[256];
    sv[tid] = best; si[tid] = bidx;
    __syncthreads();
    for (int s = 128; s > 0; s >>= 1) {
        if (tid < s) {
            float v2 = sv[tid + s]; int i2 = si[tid + s];
            if (v2 > sv[tid] || (v2 == sv[tid] && i2 < si[tid])) {
                sv[tid] = v2; si[tid] = i2;
            }
        }
        __syncthreads();
    }
    if (tid == 0)
        amax[blk] = make_int2(__float_as_int(sv[0]), si[0]);
}

// ---------------------------------------------------------------------------
// Kernel 2: dense pass. Each thread owns 16 CONTIGUOUS positions (16|80 =>
// span shares one (c,h) row). The 5-chunk argmax finalize is folded into the
// tid<32 setup phase. No global atomics: one float4 partial per block.
// ---------------------------------------------------------------------------
constexpr int K2_PER_THREAD = 16;
constexpr int K2_BLOCK_ELEMS = 256 * K2_PER_THREAD;          // 4096
constexpr int K2_BLOCKS_PER_BATCH = CHW / K2_BLOCK_ELEMS;    // 100
constexpr int NBLK = B * K2_BLOCKS_PER_BATCH;                // 1600

__global__ __launch_bounds__(256) void main_kernel(
    const float* __restrict__ pred,
    const float* __restrict__ conf,
    const float* __restrict__ gtb,
    const int*   __restrict__ gtl,
    const int2*  __restrict__ amax,
    float4* __restrict__ partials)
{
    const int tid = threadIdx.x;
    const int b = blockIdx.x / K2_BLOCKS_PER_BATCH;
    const int base = (blockIdx.x % K2_BLOCKS_PER_BATCH) * K2_BLOCK_ELEMS;
    const int pos0 = base + tid * K2_PER_THREAD;   // contiguous span of 16

    // ---- issue conf loads immediately ----
    const float4* conf4 = (const float4*)(conf + (size_t)b * CHW);
    float4 q[4];
#pragma unroll
    for (int k = 0; k < 4; k++) q[k] = conf4[(pos0 >> 2) + k];

    // span geometry
    const int c = pos0 / HW;
    const int rem = pos0 - c * HW;
    const int h = rem / Wd;
    const int w0 = rem - h * Wd;

    __shared__ int s_cnt;
    __shared__ int4 s_gt[N];   // {g, lab, mi, mj} for valid gts in channel range
    if (tid == 0) s_cnt = 0;
    __syncthreads();
    const int c0 = base / HW;
    const int c1 = (base + K2_BLOCK_ELEMS - 1) / HW;
    if (tid < N) {
        const int bg = b * N + tid;
        // finalize argmax across the 5 chunk partials (L2-hit loads)
        float best = -INFINITY;
        int idx = 0x7fffffff;
#pragma unroll
        for (int kc = 0; kc < NCHUNK; kc++) {
            int2 pr = amax[bg * NCHUNK + kc];
            float v = __int_as_float(pr.x);
            if (v > best || (v == best && pr.y < idx)) { best = v; idx = pr.y; }
        }
        if (best > 0.3f) {
            int lab = gtl[bg];
            if (lab >= c0 && lab <= c1) {
                int k = atomicAdd(&s_cnt, 1);    // LDS atomic
                s_gt[k] = make_int4(tid, lab, idx / Wd, idx % Wd);
            }
        }
    }
    __syncthreads();
    const int cnt = s_cnt;

    // match per element
    int m[K2_PER_THREAD];
#pragma unroll
    for (int e = 0; e < K2_PER_THREAD; e++) m[e] = -1;
    for (int j = 0; j < cnt; j++) {
        int4 a = s_gt[j];
        if (a.y == c && h >= a.z - 2 && h <= a.z + 1) {
#pragma unroll
            for (int e = 0; e < K2_PER_THREAD; e++) {
                int w = w0 + e;
                if (w >= a.w - 2 && w <= a.w + 1) m[e] = max(m[e], a.x);
            }
        }
    }

    float pv[K2_PER_THREAD];
#pragma unroll
    for (int k = 0; k < 4; k++) {
        pv[4 * k + 0] = q[k].x; pv[4 * k + 1] = q[k].y;
        pv[4 * k + 2] = q[k].z; pv[4 * k + 3] = q[k].w;
    }

    float l_l1 = 0.0f, l_gi = 0.0f, l_f = 0.0f, l_np = 0.0f;

#pragma unroll
    for (int e = 0; e < K2_PER_THREAD; e++) {
        float p = fminf(fmaxf(pv[e], 1e-6f), 1.0f - 1e-6f);
        if (m[e] >= 0) {
#pragma clang fp contract(off)
            // positive: focal t=1, plus L1 + GIoU (rare path)
            float om = 1.0f - p;
            l_f += 0.25f * om * om * (-__logf(p));
            l_np += 1.0f;

            int pos = pos0 + e;
            float4 pb = *(const float4*)(pred + ((size_t)b * CHW + pos) * 4);
            float4 gb = ((const float4*)gtb)[b * N + m[e]];
            l_l1 += 0.25f * (fabsf(pb.x - gb.x) + fabsf(pb.y - gb.y) +
                             fabsf(pb.z - gb.z) + fabsf(pb.w - gb.w));

            float a1 = (pb.z - pb.x) * (pb.w - pb.y);
            float a2 = (gb.z - gb.x) * (gb.w - gb.y);
            float ltx = fmaxf(pb.x, gb.x), lty = fmaxf(pb.y, gb.y);
            float rbx = fminf(pb.z, gb.z), rby = fminf(pb.w, gb.w);
            float wx = fmaxf(rbx - ltx, 0.0f), wy = fmaxf(rby - lty, 0.0f);
            float inter = wx * wy;
            float uni = (a1 + a2) - inter;
            float iou = inter / uni;
            float lex = fminf(pb.x, gb.x), ley = fminf(pb.y, gb.y);
            float rex = fmaxf(pb.z, gb.z), rey = fmaxf(pb.w, gb.w);
            float ex = fmaxf(rex - lex, 0.0f), ey = fmaxf(rey - ley, 0.0f);
            float ae = ex * ey;
            float gi = iou - (ae - uni) / ae;
            l_gi += 1.0f - gi;
        } else {
            // negative: focal t=0.  log1p(-p) == log(1-p); 1-p is Sterbenz-
            // exact for p>=0.5, and for p<0.5 there is no cancellation.
            l_f += 0.75f * p * p * (-__logf(1.0f - p));
        }
    }

    // block reduction -> one float4 partial per block (no global atomics)
    __shared__ float r0[256], r1[256], r2[256], r3[256];
    r0[tid] = l_l1; r1[tid] = l_gi; r2[tid] = l_f; r3[tid] = l_np;
    __syncthreads();
    for (int s = 128; s > 0; s >>= 1) {
        if (tid < s) {
            r0[tid] += r0[tid + s];
            r1[tid] += r1[tid + s];
            r2[tid] += r2[tid + s];
            r3[tid] += r3[tid + s];
        }
        __syncthreads();
    }
    if (tid == 0)
        partials[blockIdx.x] = make_float4(r0[0], r1[0], r2[0], r3[0]);
}

// ---------------------------------------------------------------------------
// Kernel 3: reduce NBLK partials, finalize 5 scalars.
// ---------------------------------------------------------------------------
__global__ __launch_bounds__(256) void final_kernel(
    const float4* __restrict__ partials,
    float* __restrict__ out)
{
    const int tid = threadIdx.x;
    float s0 = 0.0f, s1 = 0.0f, s2 = 0.0f, s3 = 0.0f;
    for (int i = tid; i < NBLK; i += 256) {
        float4 p = partials[i];
        s0 += p.x; s1 += p.y; s2 += p.z; s3 += p.w;
    }
    __shared__ float r0[256], r1[256], r2[256], r3[256];
    r0[tid] = s0; r1[tid] = s1; r2[tid] = s2; r3[tid] = s3;
    __syncthreads();
    for (int s = 128; s > 0; s >>= 1) {
        if (tid < s) {
            r0[tid] += r0[tid + s];
            r1[tid] += r1[tid + s];
            r2[tid] += r2[tid + s];
            r3[tid] += r3[tid + s];
        }
        __syncthreads();
    }
    if (tid == 0) {
        float np = r3[0];
        float denom = fmaxf(np, 1.0f);
        float l1 = r0[0] / denom;
        float gi = r1[0] / denom;
        float cf = r2[0] / (float)TOTAL;
        out[0] = l1;
        out[1] = gi;
        out[2] = cf;
        out[3] = l1 + 2.0f * gi + cf;
        out[4] = np / (float)TOTAL;
    }
}

extern "C" void kernel_launch(void* const* d_in, const int* in_sizes, int n_in,
                              void* d_out, int out_size, void* d_ws, size_t ws_size,
                              hipStream_t stream) {
    const float* pred = (const float*)d_in[0];  // [B,C,H,W,4]
    const float* conf = (const float*)d_in[1];  // [B,C,H,W]
    // d_in[2] = cam: unused by the loss
    const float* gtb  = (const float*)d_in[3];  // [B,N,4]
    const int*   gtl  = (const int*)d_in[4];    // [B,N]

    int2*   amax     = (int2*)d_ws;                          // 512*5*8 = 20480 B
    float4* partials = (float4*)((char*)d_ws + 32768);       // 1600*16 B
    float*  out      = (float*)d_out;

    assign_partial_kernel<<<B * N * NCHUNK, 256, 0, stream>>>(pred, gtb, gtl, amax);
    main_kernel<<<NBLK, 256, 0, stream>>>(pred, conf, gtb, gtl, amax, partials);
    final_kernel<<<1, 256, 0, stream>>>(partials, out);
}

// Round 5
// 188.095 us; speedup vs baseline: 1.8252x; 1.0109x over previous
//
#include <hip/hip_runtime.h>
#include <math.h>

// Problem constants (from setup_inputs): B=16, C=64, H=80, W=80, N=32
constexpr int B = 16, C = 64, H = 80, Wd = 80, N = 32;
constexpr int HW = H * Wd;          // 6400
constexpr int CHW = C * HW;         // 409600
constexpr long long TOTAL = (long long)B * CHW;  // 6,553,600

// Argmax split: 5 chunks of 1280 positions per (b,g)
constexpr int NCHUNK = 5;
constexpr int CHUNK_ELEMS = HW / NCHUNK;   // 1280
constexpr int A_DEPTH = CHUNK_ELEMS / 256; // 5 float4 per thread (no spill)

// Workspace layout:
//   [0, 512*5*8)         : int2 amax[B*N*NCHUNK]  {bits(best_giou), idx}
//   [32768, +NBLK*16)    : float4 partials[NBLK]  {l1, giou, focal, npos}

// ---------------------------------------------------------------------------
// Kernel 1 (stage A): per (b,g,chunk) partial argmax-GIoU. 2560 blocks.
// GIoU math: contract(off) + exact numpy op order -> bitwise-identical values,
// so argmax with first-index tie-break matches the reference.
// Reduction: 6-step wave shuffle + single-barrier cross-wave merge.
// ---------------------------------------------------------------------------
__global__ __launch_bounds__(256) void assign_partial_kernel(
    const float* __restrict__ pred,   // [B,C,H,W,4]
    const float* __restrict__ gtb,    // [B,N,4]
    const int*   __restrict__ gtl,    // [B,N]
    int2* __restrict__ amax)          // [B*N*NCHUNK]
{
#pragma clang fp contract(off)
    const int blk = blockIdx.x;
    const int bg = blk / NCHUNK;          // 0..511
    const int chunk = blk - bg * NCHUNK;  // 0..4
    const int b = bg >> 5;
    const int tid = threadIdx.x;

    const int lab = gtl[bg];
    const float4 gb = ((const float4*)gtb)[bg];
    const float a2 = (gb.z - gb.x) * (gb.w - gb.y);

    const float4* pc = (const float4*)(pred + (size_t)(b * C + lab) * HW * 4)
                       + chunk * CHUNK_ELEMS;

    // prefetch: 5 independent 16B loads in flight
    float4 buf[A_DEPTH];
#pragma unroll
    for (int k = 0; k < A_DEPTH; k++)
        buf[k] = pc[tid + k * 256];

    float best = -INFINITY;
    int bidx = 0x7fffffff;
#pragma unroll
    for (int k = 0; k < A_DEPTH; k++) {
        float4 pb = buf[k];
        float a1 = (pb.z - pb.x) * (pb.w - pb.y);
        float ltx = fmaxf(pb.x, gb.x), lty = fmaxf(pb.y, gb.y);
        float rbx = fminf(pb.z, gb.z), rby = fminf(pb.w, gb.w);
        float wx = fmaxf(rbx - ltx, 0.0f), wy = fmaxf(rby - lty, 0.0f);
        float inter = wx * wy;
        float uni = (a1 + a2) - inter;
        float iou = inter / uni;
        float lex = fminf(pb.x, gb.x), ley = fminf(pb.y, gb.y);
        float rex = fmaxf(pb.z, gb.z), rey = fmaxf(pb.w, gb.w);
        float ex = fmaxf(rex - lex, 0.0f), ey = fmaxf(rey - ley, 0.0f);
        float ae = ex * ey;
        float gi = iou - (ae - uni) / ae;
        if (gi > best) { best = gi; bidx = chunk * CHUNK_ELEMS + tid + k * 256; }
    }

    // wave-level argmax (64 lanes, 6 shuffle steps, no barriers)
#pragma unroll
    for (int off = 32; off > 0; off >>= 1) {
        float ov = __shfl_down(best, off, 64);
        int   oi = __shfl_down(bidx, off, 64);
        if (ov > best || (ov == best && oi < bidx)) { best = ov; bidx = oi; }
    }

    // cross-wave merge (4 waves) via tiny LDS + one barrier
    __shared__ float sv[4];
    __shared__ int   si[4];
    if ((tid & 63) == 0) { sv[tid >> 6] = best; si[tid >> 6] = bidx; }
    __syncthreads();
    if (tid == 0) {
        float bv = sv[0]; int bi = si[0];
#pragma unroll
        for (int wv = 1; wv < 4; wv++) {
            if (sv[wv] > bv || (sv[wv] == bv && si[wv] < bi)) {
                bv = sv[wv]; bi = si[wv];
            }
        }
        amax[blk] = make_int2(__float_as_int(bv), bi);
    }
}

// ---------------------------------------------------------------------------
// Kernel 2: dense pass. Each thread owns 16 CONTIGUOUS positions (16|80 =>
// span shares one (c,h) row). Dense path is BRANCHLESS negative-focal only
// (~12 instr/elem); positives (block-uniform rare) are corrected afterwards.
// ---------------------------------------------------------------------------
constexpr int K2_PER_THREAD = 16;
constexpr int K2_BLOCK_ELEMS = 256 * K2_PER_THREAD;          // 4096
constexpr int K2_BLOCKS_PER_BATCH = CHW / K2_BLOCK_ELEMS;    // 100
constexpr int NBLK = B * K2_BLOCKS_PER_BATCH;                // 1600

__global__ __launch_bounds__(256) void main_kernel(
    const float* __restrict__ pred,
    const float* __restrict__ conf,
    const float* __restrict__ gtb,
    const int*   __restrict__ gtl,
    const int2*  __restrict__ amax,
    float4* __restrict__ partials)
{
    const int tid = threadIdx.x;
    const int b = blockIdx.x / K2_BLOCKS_PER_BATCH;
    const int base = (blockIdx.x % K2_BLOCKS_PER_BATCH) * K2_BLOCK_ELEMS;
    const int pos0 = base + tid * K2_PER_THREAD;   // contiguous span of 16

    // ---- issue conf loads immediately ----
    const float4* conf4 = (const float4*)(conf + (size_t)b * CHW);
    float4 q[4];
#pragma unroll
    for (int k = 0; k < 4; k++) q[k] = conf4[(pos0 >> 2) + k];

    // span geometry
    const int c = pos0 / HW;
    const int rem = pos0 - c * HW;
    const int h = rem / Wd;
    const int w0 = rem - h * Wd;

    __shared__ int s_cnt;
    __shared__ int4 s_gt[N];   // {g, lab, mi, mj} for valid gts in channel range
    if (tid == 0) s_cnt = 0;
    __syncthreads();
    const int c0 = base / HW;
    const int c1 = (base + K2_BLOCK_ELEMS - 1) / HW;
    if (tid < N) {
        const int bg = b * N + tid;
        float best = -INFINITY;
        int idx = 0x7fffffff;
#pragma unroll
        for (int kc = 0; kc < NCHUNK; kc++) {
            int2 pr = amax[bg * NCHUNK + kc];
            float v = __int_as_float(pr.x);
            if (v > best || (v == best && pr.y < idx)) { best = v; idx = pr.y; }
        }
        if (best > 0.3f) {
            int lab = gtl[bg];
            if (lab >= c0 && lab <= c1) {
                int k = atomicAdd(&s_cnt, 1);    // LDS atomic
                s_gt[k] = make_int4(tid, lab, idx / Wd, idx % Wd);
            }
        }
    }
    __syncthreads();
    const int cnt = s_cnt;

    float pv[K2_PER_THREAD];
#pragma unroll
    for (int k = 0; k < 4; k++) {
        pv[4 * k + 0] = q[k].x; pv[4 * k + 1] = q[k].y;
        pv[4 * k + 2] = q[k].z; pv[4 * k + 3] = q[k].w;
    }

    // ---- dense branchless pass: assume every element is negative ----
    float l_f = 0.0f;
#pragma unroll
    for (int e = 0; e < K2_PER_THREAD; e++) {
        float p = fminf(fmaxf(pv[e], 1e-6f), 1.0f - 1e-6f);
        l_f += 0.75f * p * p * (-__logf(1.0f - p));
    }

    // ---- rare positive corrections (cnt is block-uniform; usually 0) ----
    float l_l1 = 0.0f, l_gi = 0.0f, l_np = 0.0f;
    if (cnt) {
        int m[K2_PER_THREAD];
#pragma unroll
        for (int e = 0; e < K2_PER_THREAD; e++) m[e] = -1;
        for (int j = 0; j < cnt; j++) {
            int4 a = s_gt[j];
            if (a.y == c && h >= a.z - 2 && h <= a.z + 1) {
#pragma unroll
                for (int e = 0; e < K2_PER_THREAD; e++) {
                    int w = w0 + e;
                    if (w >= a.w - 2 && w <= a.w + 1) m[e] = max(m[e], a.x);
                }
            }
        }
#pragma unroll
        for (int e = 0; e < K2_PER_THREAD; e++) {
            if (m[e] >= 0) {
#pragma clang fp contract(off)
                float p = fminf(fmaxf(pv[e], 1e-6f), 1.0f - 1e-6f);
                float om = 1.0f - p;
                // swap neg focal term for pos focal term
                l_f += 0.25f * om * om * (-__logf(p))
                     - 0.75f * p * p * (-__logf(1.0f - p));
                l_np += 1.0f;

                int pos = pos0 + e;
                float4 pb = *(const float4*)(pred + ((size_t)b * CHW + pos) * 4);
                float4 gb = ((const float4*)gtb)[b * N + m[e]];
                l_l1 += 0.25f * (fabsf(pb.x - gb.x) + fabsf(pb.y - gb.y) +
                                 fabsf(pb.z - gb.z) + fabsf(pb.w - gb.w));

                float a1 = (pb.z - pb.x) * (pb.w - pb.y);
                float a2 = (gb.z - gb.x) * (gb.w - gb.y);
                float ltx = fmaxf(pb.x, gb.x), lty = fmaxf(pb.y, gb.y);
                float rbx = fminf(pb.z, gb.z), rby = fminf(pb.w, gb.w);
                float wx = fmaxf(rbx - ltx, 0.0f), wy = fmaxf(rby - lty, 0.0f);
                float inter = wx * wy;
                float uni = (a1 + a2) - inter;
                float iou = inter / uni;
                float lex = fminf(pb.x, gb.x), ley = fminf(pb.y, gb.y);
                float rex = fmaxf(pb.z, gb.z), rey = fmaxf(pb.w, gb.w);
                float ex = fmaxf(rex - lex, 0.0f), ey = fmaxf(rey - ley, 0.0f);
                float ae = ex * ey;
                float gi = iou - (ae - uni) / ae;
                l_gi += 1.0f - gi;
            }
        }
    }

    // ---- reduction: wave shuffle (6 steps) + single-barrier cross-wave ----
#pragma unroll
    for (int off = 32; off > 0; off >>= 1) {
        l_l1 += __shfl_down(l_l1, off, 64);
        l_gi += __shfl_down(l_gi, off, 64);
        l_f  += __shfl_down(l_f,  off, 64);
        l_np += __shfl_down(l_np, off, 64);
    }
    __shared__ float4 swv[4];
    if ((tid & 63) == 0) swv[tid >> 6] = make_float4(l_l1, l_gi, l_f, l_np);
    __syncthreads();
    if (tid == 0) {
        float4 s = swv[0];
#pragma unroll
        for (int wv = 1; wv < 4; wv++) {
            s.x += swv[wv].x; s.y += swv[wv].y;
            s.z += swv[wv].z; s.w += swv[wv].w;
        }
        partials[blockIdx.x] = s;
    }
}

// ---------------------------------------------------------------------------
// Kernel 3: reduce NBLK partials, finalize 5 scalars.
// ---------------------------------------------------------------------------
__global__ __launch_bounds__(256) void final_kernel(
    const float4* __restrict__ partials,
    float* __restrict__ out)
{
    const int tid = threadIdx.x;
    float s0 = 0.0f, s1 = 0.0f, s2 = 0.0f, s3 = 0.0f;
    for (int i = tid; i < NBLK; i += 256) {
        float4 p = partials[i];
        s0 += p.x; s1 += p.y; s2 += p.z; s3 += p.w;
    }
#pragma unroll
    for (int off = 32; off > 0; off >>= 1) {
        s0 += __shfl_down(s0, off, 64);
        s1 += __shfl_down(s1, off, 64);
        s2 += __shfl_down(s2, off, 64);
        s3 += __shfl_down(s3, off, 64);
    }
    __shared__ float4 swv[4];
    if ((tid & 63) == 0) swv[tid >> 6] = make_float4(s0, s1, s2, s3);
    __syncthreads();
    if (tid == 0) {
        float4 s = swv[0];
#pragma unroll
        for (int wv = 1; wv < 4; wv++) {
            s.x += swv[wv].x; s.y += swv[wv].y;
            s.z += swv[wv].z; s.w += swv[wv].w;
        }
        float np = s.w;
        float denom = fmaxf(np, 1.0f);
        float l1 = s.x / denom;
        float gi = s.y / denom;
        float cf = s.z / (float)TOTAL;
        out[0] = l1;
        out[1] = gi;
        out[2] = cf;
        out[3] = l1 + 2.0f * gi + cf;
        out[4] = np / (float)TOTAL;
    }
}

extern "C" void kernel_launch(void* const* d_in, const int* in_sizes, int n_in,
                              void* d_out, int out_size, void* d_ws, size_t ws_size,
                              hipStream_t stream) {
    const float* pred = (const float*)d_in[0];  // [B,C,H,W,4]
    const float* conf = (const float*)d_in[1];  // [B,C,H,W]
    // d_in[2] = cam: unused by the loss
    const float* gtb  = (const float*)d_in[3];  // [B,N,4]
    const int*   gtl  = (const int*)d_in[4];    // [B,N]

    int2*   amax     = (int2*)d_ws;                          // 512*5*8 = 20480 B
    float4* partials = (float4*)((char*)d_ws + 32768);       // 1600*16 B
    float*  out      = (float*)d_out;

    assign_partial_kernel<<<B * N * NCHUNK, 256, 0, stream>>>(pred, gtb, gtl, amax);
    main_kernel<<<NBLK, 256, 0, stream>>>(pred, conf, gtb, gtl, amax, partials);
    final_kernel<<<1, 256, 0, stream>>>(partials, out);
}